// Round 7
// baseline (286.321 us; speedup 1.0000x reference)
//
#include <hip/hip_runtime.h>
#include <hip/hip_cooperative_groups.h>

namespace cg = cooperative_groups;

#define Bn 32
#define Tn 256
#define Cn 512
#define Ln 25

typedef _Float16 h8 __attribute__((ext_vector_type(8)));
typedef __attribute__((ext_vector_type(4))) float f32x4;

#define SCALE2LOG2E 2.885390081777927f   // 2*log2(e)

#if __has_builtin(__builtin_amdgcn_exp2f)
#define EXP2(x) __builtin_amdgcn_exp2f(x)
#else
#define EXP2(x) __expf(0.69314718056f * (x))
#endif

// sum across 16-lane groups on VALU pipe: xor1, xor2, xor7, xor15 pairings
#define DPP_ADD(v, ctrl) \
    ((v) + __int_as_float(__builtin_amdgcn_update_dpp(0, __float_as_int(v), ctrl, 0xf, 0xf, true)))

#define NA_OCT (Bn * Tn * Cn / 8)           // 524288
#define NW_OCT (Cn * Cn / 8)                // 32768

__global__ __launch_bounds__(512, 2) void k_mega(
        const float* __restrict__ A, const float* __restrict__ W,
        const float* __restrict__ bias, const float* __restrict__ pos,
        const float* __restrict__ aw,
        float* __restrict__ wf, float* __restrict__ scores, float* __restrict__ P,
        _Float16* __restrict__ A2, _Float16* __restrict__ W2,
        float* __restrict__ out) {
    __shared__ union {
        struct { _Float16 As[128 * 64]; _Float16 Ws[64 * 64]; } g;  // 24 KB
        float part[4 * Ln * 8];                                     // 3.2 KB
        float sm[Ln * Tn];                                          // 25.6 KB
        float red[8 * Ln * 64];                                     // 51.2 KB
    } su;
    cg::grid_group grid = cg::this_grid();
    const int tid  = threadIdx.x;
    const int lane = tid & 63;
    const int wv   = tid >> 6;
    const int bid  = blockIdx.x;

    // ---- P0: convert fp32 -> fp16 (A and W, flat) ----
    for (int idx = bid * 512 + tid; idx < NA_OCT + NW_OCT; idx += 256 * 512) {
        const float* src; _Float16* dst; int off;
        if (idx < NA_OCT) { src = A; dst = A2; off = idx * 8; }
        else              { src = W; dst = W2; off = (idx - NA_OCT) * 8; }
        float4 v0 = *(const float4*)&src[off];
        float4 v1 = *(const float4*)&src[off + 4];
        h8 o;
        o[0] = (_Float16)v0.x; o[1] = (_Float16)v0.y;
        o[2] = (_Float16)v0.z; o[3] = (_Float16)v0.w;
        o[4] = (_Float16)v1.x; o[5] = (_Float16)v1.y;
        o[6] = (_Float16)v1.z; o[7] = (_Float16)v1.w;
        *(h8*)&dst[off] = o;
    }
    grid.sync();

    // ---- P1: gemm wf = A2·W2^T + bias  (fp16 MFMA, K=512, tile 128x64, 8 waves 4m x 2n)
    // XOR-swizzled LDS: logical chunk lk of row at phys pk = lk ^ (row&7)
    {
        const int wm = (wv >> 1) * 32;
        const int wn = (wv & 1) * 32;
        const int r = lane & 15, q = lane >> 4;
        for (int tile = bid; tile < 512; tile += 256) {
            const int m0 = (tile >> 3) * 128;
            const int n0 = (tile & 7) * 64;
            f32x4 acc[2][2];
            #pragma unroll
            for (int mi = 0; mi < 2; ++mi)
                #pragma unroll
                for (int ni = 0; ni < 2; ++ni) acc[mi][ni] = (f32x4){0.f, 0.f, 0.f, 0.f};

            for (int kt = 0; kt < 8; ++kt) {
                __syncthreads();
                #pragma unroll
                for (int rr = 0; rr < 2; ++rr) {
                    int p = rr * 512 + tid;
                    int row = p >> 3, pk = p & 7;
                    int lk = pk ^ (row & 7);
                    __builtin_amdgcn_global_load_lds(
                        (const __attribute__((address_space(1))) unsigned int*)
                            (A2 + (size_t)(m0 + row) * Cn + kt * 64 + lk * 8),
                        (__attribute__((address_space(3))) unsigned int*)
                            (su.g.As + (rr * 512 + wv * 64) * 8),
                        16, 0, 0);
                }
                {
                    int p = tid;
                    int row = p >> 3, pk = p & 7;
                    int lk = pk ^ (row & 7);
                    __builtin_amdgcn_global_load_lds(
                        (const __attribute__((address_space(1))) unsigned int*)
                            (W2 + (size_t)(n0 + row) * Cn + kt * 64 + lk * 8),
                        (__attribute__((address_space(3))) unsigned int*)
                            (su.g.Ws + (wv * 64) * 8),
                        16, 0, 0);
                }
                __syncthreads();

                h8 af[2][2], bfr[2][2];
                #pragma unroll
                for (int mi = 0; mi < 2; ++mi)
                    #pragma unroll
                    for (int kk = 0; kk < 2; ++kk) {
                        int row = wm + mi * 16 + r;
                        int phys = (kk * 4 + q) ^ (r & 7);
                        af[mi][kk] = *(const h8*)&su.g.As[row * 64 + phys * 8];
                    }
                #pragma unroll
                for (int ni = 0; ni < 2; ++ni)
                    #pragma unroll
                    for (int kk = 0; kk < 2; ++kk) {
                        int row = wn + ni * 16 + r;
                        int phys = (kk * 4 + q) ^ (r & 7);
                        bfr[ni][kk] = *(const h8*)&su.g.Ws[row * 64 + phys * 8];
                    }
                #pragma unroll
                for (int kk = 0; kk < 2; ++kk)
                    #pragma unroll
                    for (int mi = 0; mi < 2; ++mi)
                        #pragma unroll
                        for (int ni = 0; ni < 2; ++ni)
                            acc[mi][ni] = __builtin_amdgcn_mfma_f32_16x16x32_f16(
                                af[mi][kk], bfr[ni][kk], acc[mi][ni], 0, 0, 0);
            }

            #pragma unroll
            for (int ni = 0; ni < 2; ++ni) {
                const float bv = bias[n0 + wn + ni * 16 + r];
                #pragma unroll
                for (int mi = 0; mi < 2; ++mi)
                    #pragma unroll
                    for (int reg = 0; reg < 4; ++reg) {
                        int row = m0 + wm + mi * 16 + q * 4 + reg;
                        int col = n0 + wn + ni * 16 + r;
                        wf[(size_t)row * Cn + col] = acc[mi][ni][reg] + bv;
                    }
            }
            __syncthreads();
        }
    }
    grid.sync();

    // ---- P2: scores[b][l][t] = sum(aw) - 2*sum(aw * 1/(1+exp2(SCALE*(wf+pos))))
    {
        const int tl = wv >> 1;              // local t 0..3
        const int ch = wv & 1;               // c half
        const int co = ch * 256 + lane * 4;
        const float4 a = *(const float4*)&aw[co];
        const float U = (a.x + a.y) + (a.z + a.w);
        float4 u;
        u.x = -2.f * a.x; u.y = -2.f * a.y; u.z = -2.f * a.z; u.w = -2.f * a.w;
        const float* pp = pos + co;
        float* prt = &su.part[tl * Ln * 8 + ch * 4 + (lane >> 4)];
        const bool writer = ((lane & 15) == 0);

        for (int wk = bid; wk < 2048; wk += 256) {
            const int tx = wk & 63, b = wk >> 6;
            const int t = tx * 4 + tl;
            float4 w = *(const float4*)&wf[(size_t)(b * Tn + t) * Cn + co];
            w.x *= SCALE2LOG2E; w.y *= SCALE2LOG2E; w.z *= SCALE2LOG2E; w.w *= SCALE2LOG2E;

            #pragma unroll
            for (int lo = 0; lo < 5; ++lo) {
                float4 pv[5];
                #pragma unroll
                for (int j = 0; j < 5; ++j)
                    pv[j] = *(const float4*)(pp + (lo * 5 + j) * Cn);
                #pragma unroll
                for (int j = 0; j < 5; ++j) {
                    const float4 p = pv[j];
                    float s = U;
                    s = fmaf(u.x, __builtin_amdgcn_rcpf(1.f + EXP2(fmaf(SCALE2LOG2E, p.x, w.x))), s);
                    s = fmaf(u.y, __builtin_amdgcn_rcpf(1.f + EXP2(fmaf(SCALE2LOG2E, p.y, w.y))), s);
                    s = fmaf(u.z, __builtin_amdgcn_rcpf(1.f + EXP2(fmaf(SCALE2LOG2E, p.z, w.z))), s);
                    s = fmaf(u.w, __builtin_amdgcn_rcpf(1.f + EXP2(fmaf(SCALE2LOG2E, p.w, w.w))), s);
                    s = DPP_ADD(s, 0xB1);    // xor 1
                    s = DPP_ADD(s, 0x4E);    // xor 2
                    s = DPP_ADD(s, 0x141);   // row_half_mirror (xor 7)
                    s = DPP_ADD(s, 0x140);   // row_mirror (xor 15)
                    if (writer) prt[(lo * 5 + j) * 8] = s;
                }
            }
            __syncthreads();
            if (tid < 4 * Ln) {
                int tl2 = tid / Ln, l2 = tid - tl2 * Ln;
                const float* q2 = &su.part[(tl2 * Ln + l2) * 8];
                float v = ((q2[0] + q2[1]) + (q2[2] + q2[3])) + ((q2[4] + q2[5]) + (q2[6] + q2[7]));
                scores[(size_t)(b * Ln + l2) * Tn + tx * 4 + tl2] = v;
            }
            __syncthreads();
        }
    }
    grid.sync();

    // ---- P3: softmax over t -> P[b][t][32] (l-major padded rows) ----
    if (bid < Bn) {
        const int b = bid;
        const float* sc = scores + (size_t)b * Ln * Tn;
        for (int i = tid * 4; i < Ln * Tn; i += 2048)
            *(float4*)&su.sm[i] = *(const float4*)&sc[i];
        __syncthreads();
        for (int l = wv; l < Ln; l += 8) {
            float v0 = su.sm[l * Tn + lane];
            float v1 = su.sm[l * Tn + 64 + lane];
            float v2 = su.sm[l * Tn + 128 + lane];
            float v3 = su.sm[l * Tn + 192 + lane];
            float m = fmaxf(fmaxf(v0, v1), fmaxf(v2, v3));
            #pragma unroll
            for (int o = 32; o > 0; o >>= 1) m = fmaxf(m, __shfl_xor(m, o));
            float e0 = __expf(v0 - m), e1 = __expf(v1 - m);
            float e2 = __expf(v2 - m), e3 = __expf(v3 - m);
            float s = e0 + e1 + e2 + e3;
            #pragma unroll
            for (int o = 32; o > 0; o >>= 1) s += __shfl_xor(s, o);
            float rs = __builtin_amdgcn_rcpf(s);
            float* pr = P + ((size_t)(b * Tn) + lane) * 32 + l;
            pr[0]        = e0 * rs;
            pr[64 * 32]  = e1 * rs;
            pr[128 * 32] = e2 * rs;
            pr[192 * 32] = e3 * rs;
        }
    }
    grid.sync();

    // ---- P4: out[b][l][c] = sum_t P[b][t][l] * wf[b][t][c] ----
    {
        const int cx = bid & 7, b = bid >> 3;
        const int c = cx * 64 + lane;
        float acc[Ln];
        #pragma unroll
        for (int l = 0; l < Ln; ++l) acc[l] = 0.f;

        const float* wfp = wf + ((size_t)(b * Tn + wv * 32)) * Cn + c;
        const float* pb  = P + ((size_t)(b * Tn + wv * 32)) * 32;
        for (int tt = 0; tt < 32; ++tt) {
            float w = wfp[tt * Cn];
            float p[28];
            #pragma unroll
            for (int j = 0; j < 7; ++j)
                *(float4*)&p[j * 4] = *(const float4*)(pb + tt * 32 + j * 4);
            #pragma unroll
            for (int l = 0; l < Ln; ++l) acc[l] = fmaf(p[l], w, acc[l]);
        }

        __syncthreads();
        #pragma unroll
        for (int l = 0; l < Ln; ++l)
            su.red[(wv * Ln + l) * 64 + lane] = acc[l];
        __syncthreads();
        for (int i = tid; i < Ln * 64; i += 512) {
            int l = i >> 6, cc = i & 63;
            float v = 0.f;
            #pragma unroll
            for (int w8 = 0; w8 < 8; ++w8) v += su.red[(w8 * Ln + l) * 64 + cc];
            out[((size_t)b * Ln + l) * Cn + cx * 64 + cc] = v;
        }
    }
}

extern "C" void kernel_launch(void* const* d_in, const int* in_sizes, int n_in,
                              void* d_out, int out_size, void* d_ws, size_t ws_size,
                              hipStream_t stream) {
    const float* A    = (const float*)d_in[0];
    const float* W    = (const float*)d_in[1];
    const float* bias = (const float*)d_in[2];
    const float* pos  = (const float*)d_in[3];
    const float* aw   = (const float*)d_in[4];

    char* ws = (char*)d_ws;
    float*     wf     = (float*)ws;                          // 16.78 MB
    float*     scores = (float*)(ws + 16777216ull);          // 0.82 MB
    float*     P      = (float*)(ws + 17596416ull);          // 1.05 MB  [b][t][32]
    _Float16*  A2     = (_Float16*)(ws + 18644992ull);       // 8.39 MB
    _Float16*  W2     = (_Float16*)(ws + 27033600ull);       // 0.52 MB
    float* outp = (float*)d_out;

    void* args[] = { (void*)&A, (void*)&W, (void*)&bias, (void*)&pos, (void*)&aw,
                     (void*)&wf, (void*)&scores, (void*)&P, (void*)&A2, (void*)&W2,
                     (void*)&outp };
    hipLaunchCooperativeKernel((const void*)k_mega, dim3(256), dim3(512), args, 0, stream);
}

// Round 8
// 123.207 us; speedup vs baseline: 2.3239x; 2.3239x over previous
//
#include <hip/hip_runtime.h>

#define Bn 32
#define Tn 256
#define Cn 512
#define Ln 25

typedef _Float16 h8 __attribute__((ext_vector_type(8)));
typedef __attribute__((ext_vector_type(4))) float f32x4;

#define SCALE2LOG2E 2.885390081777927f   // 2*log2(e)

#if __has_builtin(__builtin_amdgcn_exp2f)
#define EXP2(x) __builtin_amdgcn_exp2f(x)
#else
#define EXP2(x) __expf(0.69314718056f * (x))
#endif

// sum across 16-lane groups on VALU pipe: xor1, xor2, xor7, xor15 pairings
#define DPP_ADD(v, ctrl) \
    ((v) + __int_as_float(__builtin_amdgcn_update_dpp(0, __float_as_int(v), ctrl, 0xf, 0xf, true)))

// K1: wf = A(fp32)·W(fp32)^T + bias via fp16 MFMA with in-register conversion.
// Tile 128m x 128n, BK=32 halves, 512 thr = 8 waves (2m x 4n, wave-tile 64x32).
// LDS rows stride 40 halves (80B) to spread banks; staged by ds_write_b128.
#define BM 128
#define BN 128
#define BKh 32
#define LDST 40
__global__ __launch_bounds__(512, 4) void k_gemm(
        const float* __restrict__ A, const float* __restrict__ W,
        const float* __restrict__ bias, float* __restrict__ wf) {
    __shared__ _Float16 As[BM * LDST];   // 10.24 KB
    __shared__ _Float16 Ws[BN * LDST];   // 10.24 KB
    const int tid  = threadIdx.x;
    const int lane = tid & 63;
    const int wv   = tid >> 6;
    const int n0 = blockIdx.x * BN;
    const int m0 = blockIdx.y * BM;
    const int wm = (wv & 1) * 64;
    const int wn = (wv >> 1) * 32;
    const int r = lane & 15, q = lane >> 4;

    // staging: thread tid handles A chunk tid and W chunk tid (8 halves each)
    const int srow = tid >> 2;           // 0..127
    const int skc  = tid & 3;            // 8-half chunk within BK=32
    const float* gA = A + (size_t)(m0 + srow) * Cn + skc * 8;
    const float* gW = W + (size_t)(n0 + srow) * Cn + skc * 8;
    _Float16* lA = &As[srow * LDST + skc * 8];
    _Float16* lW = &Ws[srow * LDST + skc * 8];

    f32x4 acc[4][2];
    #pragma unroll
    for (int mi = 0; mi < 4; ++mi)
        #pragma unroll
        for (int ni = 0; ni < 2; ++ni) acc[mi][ni] = (f32x4){0.f, 0.f, 0.f, 0.f};

    float4 ra0 = *(const float4*)gA;
    float4 ra1 = *(const float4*)(gA + 4);
    float4 rw0 = *(const float4*)gW;
    float4 rw1 = *(const float4*)(gW + 4);

    for (int kt = 0; kt < Cn / BKh; ++kt) {
        if (kt > 0) __syncthreads();     // prev frag reads done before overwrite
        h8 ha, hw;
        ha[0] = (_Float16)ra0.x; ha[1] = (_Float16)ra0.y;
        ha[2] = (_Float16)ra0.z; ha[3] = (_Float16)ra0.w;
        ha[4] = (_Float16)ra1.x; ha[5] = (_Float16)ra1.y;
        ha[6] = (_Float16)ra1.z; ha[7] = (_Float16)ra1.w;
        hw[0] = (_Float16)rw0.x; hw[1] = (_Float16)rw0.y;
        hw[2] = (_Float16)rw0.z; hw[3] = (_Float16)rw0.w;
        hw[4] = (_Float16)rw1.x; hw[5] = (_Float16)rw1.y;
        hw[6] = (_Float16)rw1.z; hw[7] = (_Float16)rw1.w;
        *(h8*)lA = ha;
        *(h8*)lW = hw;
        __syncthreads();
        if (kt < Cn / BKh - 1) {         // prefetch next slab; vmcnt waited next iter
            gA += BKh; gW += BKh;
            ra0 = *(const float4*)gA;
            ra1 = *(const float4*)(gA + 4);
            rw0 = *(const float4*)gW;
            rw1 = *(const float4*)(gW + 4);
        }

        h8 af[4], bf[2];
        #pragma unroll
        for (int mi = 0; mi < 4; ++mi)
            af[mi] = *(const h8*)&As[(wm + mi * 16 + r) * LDST + q * 8];
        #pragma unroll
        for (int ni = 0; ni < 2; ++ni)
            bf[ni] = *(const h8*)&Ws[(wn + ni * 16 + r) * LDST + q * 8];
        #pragma unroll
        for (int mi = 0; mi < 4; ++mi)
            #pragma unroll
            for (int ni = 0; ni < 2; ++ni)
                acc[mi][ni] = __builtin_amdgcn_mfma_f32_16x16x32_f16(
                    af[mi], bf[ni], acc[mi][ni], 0, 0, 0);
    }

    #pragma unroll
    for (int ni = 0; ni < 2; ++ni) {
        const float bv = bias[n0 + wn + ni * 16 + r];
        #pragma unroll
        for (int mi = 0; mi < 4; ++mi)
            #pragma unroll
            for (int reg = 0; reg < 4; ++reg) {
                int row = m0 + wm + mi * 16 + q * 4 + reg;
                int col = n0 + wn + ni * 16 + r;
                wf[(size_t)row * Cn + col] = acc[mi][ni][reg] + bv;
            }
    }
}

// K2: scores[b][l][t] = sum_c tanh(wf+pos)*aw = sum(aw) - 2*sum(aw*logistic)
// 512 thr = 8 waves: wave = (t_local 0..3) x (c-half 0..1); 4 c-elems/lane.
// 5x5 unrolled l-loop: 5 pos loads in flight, 5 independent compute+DPP chains.
__global__ __launch_bounds__(512) void k_scores(
        const float* __restrict__ wf, const float* __restrict__ pos,
        const float* __restrict__ aw, float* __restrict__ scores) {
    __shared__ float part[4 * Ln * 8];       // 3.2 KB
    const int tid  = threadIdx.x;
    const int lane = tid & 63;
    const int wv   = tid >> 6;
    const int tl   = wv >> 1;                // local t 0..3
    const int ch   = wv & 1;                 // c half
    const int t    = blockIdx.x * 4 + tl;
    const int b    = blockIdx.y;
    const int co   = ch * 256 + lane * 4;

    float4 w = *(const float4*)&wf[(b * Tn + t) * Cn + co];
    w.x *= SCALE2LOG2E; w.y *= SCALE2LOG2E; w.z *= SCALE2LOG2E; w.w *= SCALE2LOG2E;
    const float4 a = *(const float4*)&aw[co];
    const float U = (a.x + a.y) + (a.z + a.w);
    float4 u;
    u.x = -2.f * a.x; u.y = -2.f * a.y; u.z = -2.f * a.z; u.w = -2.f * a.w;

    const float* pp = pos + co;
    float* prt = &part[tl * Ln * 8 + ch * 4 + (lane >> 4)];
    const bool writer = ((lane & 15) == 0);

    #pragma unroll
    for (int lo = 0; lo < 5; ++lo) {
        float4 pv[5];
        #pragma unroll
        for (int j = 0; j < 5; ++j)
            pv[j] = *(const float4*)(pp + (lo * 5 + j) * Cn);
        #pragma unroll
        for (int j = 0; j < 5; ++j) {
            const float4 p = pv[j];
            float s = U;
            s = fmaf(u.x, __builtin_amdgcn_rcpf(1.f + EXP2(fmaf(SCALE2LOG2E, p.x, w.x))), s);
            s = fmaf(u.y, __builtin_amdgcn_rcpf(1.f + EXP2(fmaf(SCALE2LOG2E, p.y, w.y))), s);
            s = fmaf(u.z, __builtin_amdgcn_rcpf(1.f + EXP2(fmaf(SCALE2LOG2E, p.z, w.z))), s);
            s = fmaf(u.w, __builtin_amdgcn_rcpf(1.f + EXP2(fmaf(SCALE2LOG2E, p.w, w.w))), s);
            s = DPP_ADD(s, 0xB1);    // xor 1
            s = DPP_ADD(s, 0x4E);    // xor 2
            s = DPP_ADD(s, 0x141);   // row_half_mirror (xor 7)
            s = DPP_ADD(s, 0x140);   // row_mirror (xor 15)
            if (writer) prt[(lo * 5 + j) * 8] = s;
        }
    }
    __syncthreads();
    if (tid < 4 * Ln) {
        int tl2 = tid / Ln, l2 = tid - tl2 * Ln;
        const float* q = &part[(tl2 * Ln + l2) * 8];
        float v = ((q[0] + q[1]) + (q[2] + q[3])) + ((q[4] + q[5]) + (q[6] + q[7]));
        scores[(b * Ln + l2) * Tn + blockIdx.x * 4 + tl2] = v;
    }
}

// K3: softmax over t; out[b][l][c] = sum_t p[l][t] * wf[b][t][c]
// 512 threads (8 waves), block per (c-chunk of 64, b).
__global__ __launch_bounds__(512) void k_pvam(
        const float* __restrict__ wf, const float* __restrict__ scores,
        float* __restrict__ out) {
    __shared__ float buf[8 * Ln * 64];       // 51.2 KB: scores staging, then reduction
    __shared__ float pT[Tn][28];             // 28.7 KB
    const int tid = threadIdx.x;
    const int cx  = blockIdx.x;
    const int b   = blockIdx.y;

    const float* sc = scores + b * Ln * Tn;
    for (int i = tid * 4; i < Ln * Tn; i += 2048)
        *(float4*)&buf[i] = *(const float4*)&sc[i];
    __syncthreads();

    const int lane = tid & 63;
    const int wv   = tid >> 6;

    for (int l = wv; l < Ln; l += 8) {
        float v0 = buf[l * Tn + lane];
        float v1 = buf[l * Tn + 64 + lane];
        float v2 = buf[l * Tn + 128 + lane];
        float v3 = buf[l * Tn + 192 + lane];
        float m = fmaxf(fmaxf(v0, v1), fmaxf(v2, v3));
        #pragma unroll
        for (int o = 32; o > 0; o >>= 1) m = fmaxf(m, __shfl_xor(m, o));
        float e0 = __expf(v0 - m), e1 = __expf(v1 - m);
        float e2 = __expf(v2 - m), e3 = __expf(v3 - m);
        float s = e0 + e1 + e2 + e3;
        #pragma unroll
        for (int o = 32; o > 0; o >>= 1) s += __shfl_xor(s, o);
        float rs = __builtin_amdgcn_rcpf(s);
        pT[lane][l]       = e0 * rs;
        pT[64 + lane][l]  = e1 * rs;
        pT[128 + lane][l] = e2 * rs;
        pT[192 + lane][l] = e3 * rs;
    }
    __syncthreads();

    const int c = cx * 64 + lane;
    float acc[Ln];
    #pragma unroll
    for (int l = 0; l < Ln; ++l) acc[l] = 0.f;

    const float* wfp = wf + (b * Tn + wv * 32) * Cn + c;
    for (int tt = 0; tt < 32; ++tt) {
        float w = wfp[tt * Cn];
        const float* pp = &pT[wv * 32 + tt][0];
        float p[Ln];
        *(float4*)&p[0]  = *(const float4*)&pp[0];
        *(float4*)&p[4]  = *(const float4*)&pp[4];
        *(float4*)&p[8]  = *(const float4*)&pp[8];
        *(float4*)&p[12] = *(const float4*)&pp[12];
        *(float4*)&p[16] = *(const float4*)&pp[16];
        *(float4*)&p[20] = *(const float4*)&pp[20];
        p[24] = pp[24];
        #pragma unroll
        for (int l = 0; l < Ln; ++l) acc[l] = fmaf(p[l], w, acc[l]);
    }

    __syncthreads();
    #pragma unroll
    for (int l = 0; l < Ln; ++l)
        buf[(wv * Ln + l) * 64 + lane] = acc[l];
    __syncthreads();
    for (int idx = tid; idx < Ln * 64; idx += 512) {
        int l = idx >> 6, cc = idx & 63;
        float v = 0.f;
        #pragma unroll
        for (int w = 0; w < 8; ++w) v += buf[(w * Ln + l) * 64 + cc];
        out[(b * Ln + l) * Cn + cx * 64 + cc] = v;
    }
}

extern "C" void kernel_launch(void* const* d_in, const int* in_sizes, int n_in,
                              void* d_out, int out_size, void* d_ws, size_t ws_size,
                              hipStream_t stream) {
    const float* A    = (const float*)d_in[0];
    const float* W    = (const float*)d_in[1];
    const float* bias = (const float*)d_in[2];
    const float* pos  = (const float*)d_in[3];
    const float* aw   = (const float*)d_in[4];

    char* ws = (char*)d_ws;
    float* wf     = (float*)ws;                          // 16.78 MB
    float* scores = (float*)(ws + 16777216ull);          // 0.82 MB
    float* out = (float*)d_out;

    k_gemm<<<dim3(Cn / BN, (Bn * Tn) / BM), 512, 0, stream>>>(A, W, bias, wf);
    k_scores<<<dim3(Tn / 4, Bn), 512, 0, stream>>>(wf, pos, aw, scores);
    k_pvam<<<dim3(Cn / 64, Bn), 512, 0, stream>>>(wf, scores, out);
}